// Round 6
// baseline (264.556 us; speedup 1.0000x reference)
//
#include <hip/hip_runtime.h>

typedef unsigned short u16;
typedef float  f32x4  __attribute__((ext_vector_type(4)));
typedef int    i32x4  __attribute__((ext_vector_type(4)));
typedef __bf16 bf16x8 __attribute__((ext_vector_type(8)));

#define AS1 __attribute__((address_space(1)))
#define AS3 __attribute__((address_space(3)))

__device__ __forceinline__ void gload_lds16(const void* g, void* l) {
  __builtin_amdgcn_global_load_lds((AS1 void*)g, (AS3 void*)l, 16, 0, 0);
}

// Problem constants
constexpr int B_ = 8, T_ = 128, U_ = 64, D_ = 512, V_ = 1024;
constexpr int M_ = B_ * T_ * U_;   // 65536

// ---------------------------------------------------------------------------
// prep_w: W (V,D) f32 -> bf16 ws with XOR-swizzle pre-applied per 64-col
// K-tile (16B chunk c of row v stored at slot c^(v&7)); block 0 also writes
// the lengths pass-through (as f32 values).
// ---------------------------------------------------------------------------
__global__ void prep_w(const float* __restrict__ W,
                       const int* __restrict__ sl, const int* __restrict__ tl,
                       u16* __restrict__ Wb, float* __restrict__ tail) {
  if (blockIdx.x == 0 && threadIdx.x < 16) {
    const int t = threadIdx.x;
    tail[t] = (t < 8) ? (float)sl[t] : (float)tl[t - 8];
  }
  const int tid = blockIdx.x * 256 + threadIdx.x;   // 65536 threads
  const int v  = tid >> 6;
  const int cs = tid & 63;
  const float* sp = W + (size_t)v * D_ + cs * 8;
  float4 w0 = *(const float4*)sp;
  float4 w1 = *(const float4*)(sp + 4);
  union { __bf16 h[8]; i32x4 x; } pk;
  pk.h[0] = (__bf16)w0.x; pk.h[1] = (__bf16)w0.y;
  pk.h[2] = (__bf16)w0.z; pk.h[3] = (__bf16)w0.w;
  pk.h[4] = (__bf16)w1.x; pk.h[5] = (__bf16)w1.y;
  pk.h[6] = (__bf16)w1.z; pk.h[7] = (__bf16)w1.w;
  const int dc = (cs >> 3) * 8 + ((cs & 7) ^ (v & 7));
  *(i32x4*)(Wb + (size_t)v * D_ + dc * 8) = pk.x;
}

__global__ void tail_k(const int* __restrict__ sl, const int* __restrict__ tl,
                       float* __restrict__ tail) {
  const int t = threadIdx.x;
  if (t < 8)       tail[t] = (float)sl[t];
  else if (t < 16) tail[t] = (float)tl[t - 8];
}

// ---------------------------------------------------------------------------
// Barrier-free joiner GEMM.
// Block = 512 threads = 8 waves; each wave owns one (b,t) row-group:
// a 64(u) x 64(v) output tile. bn selects a 64-row W slice (64KB bf16)
// staged in LDS ONCE (one barrier); the K-loop has NO barriers:
// A-fragments are computed directly in registers from src/tgt (L1-resident,
// shared across the block's 8 waves), B-fragments are ds_read from the
// resident W slice. Fully unrolled K-loop -> compiler pipelines loads
// across MFMA with no fences. launch_bounds(512,4) caps VGPR at 128
// (16 waves/CU, 2 blocks/CU).
// ---------------------------------------------------------------------------
__global__ __launch_bounds__(512, 4) void joiner_gemm_direct(
    const float* __restrict__ src, const float* __restrict__ tgt,
    const u16* __restrict__ Wb, const float* __restrict__ bias,
    float* __restrict__ out)
{
  __shared__ __align__(16) char Bs[64 * 1024];   // 64 rows x 512 bf16, swizzled

  const int tid  = threadIdx.x;
  const int lane = tid & 63;
  const int wid  = tid >> 6;          // 0..7
  const int bn   = blockIdx.x & 15;   // v-slice 0..15
  const int btg  = blockIdx.x >> 4;   // 0..127
  const int bt   = btg * 8 + wid;     // this wave's (b,t) index 0..1023
  const int b    = bt >> 7;           // batch
  const int cl   = lane & 15;
  const int kl   = lane >> 4;         // 0..3 k-phase

  // ---- stage the W slice (64 rows x 512 cols bf16) once ----
  #pragma unroll
  for (int q = 0; q < 8; ++q) {
    const int row = wid * 8 + q;
    const u16* g = Wb + (size_t)(bn * 64 + row) * D_ + lane * 8;
    gload_lds16(g, Bs + row * 1024);
  }

  // ---- accumulators, bias-initialized ----
  f32x4 acc[4][4];
  #pragma unroll
  for (int ni = 0; ni < 4; ++ni) {
    const float bv = bias[bn * 64 + ni * 16 + cl];
    #pragma unroll
    for (int mi = 0; mi < 4; ++mi) acc[mi][ni] = f32x4{bv, bv, bv, bv};
  }

  // per-lane global bases: lane's 8-elem k-slice starts at kl*8
  const float* sp  = src + (size_t)bt * D_ + kl * 8;
  const float* tp0 = tgt + ((size_t)b * U_ + cl) * D_ + kl * 8;  // +mi*16 rows

  // B LDS byte-addr per (ni,s); kt adds kt*128 as immediate offset
  int baddr[4][2];
  #pragma unroll
  for (int ni = 0; ni < 4; ++ni) {
    const int n = ni * 16 + cl;
    #pragma unroll
    for (int s = 0; s < 2; ++s)
      baddr[ni][s] = n * 1024 + (((s * 4 + kl) ^ (n & 7)) << 4);
  }

  __syncthreads();   // W slice resident for the whole K-loop (only barrier)

  #pragma unroll
  for (int kt = 0; kt < 8; ++kt) {
    #pragma unroll
    for (int s = 0; s < 2; ++s) {
      const int kof = kt * 64 + s * 32;
      const float4 sv0 = *(const float4*)(sp + kof);
      const float4 sv1 = *(const float4*)(sp + kof + 4);
      bf16x8 af[4];
      #pragma unroll
      for (int mi = 0; mi < 4; ++mi) {
        const float* tp = tp0 + (size_t)(mi * 16) * D_ + kof;
        const float4 tv0 = *(const float4*)tp;
        const float4 tv1 = *(const float4*)(tp + 4);
        union { __bf16 h[8]; bf16x8 v; } pk;
        pk.h[0] = (__bf16)fmaxf(sv0.x + tv0.x, 0.f);
        pk.h[1] = (__bf16)fmaxf(sv0.y + tv0.y, 0.f);
        pk.h[2] = (__bf16)fmaxf(sv0.z + tv0.z, 0.f);
        pk.h[3] = (__bf16)fmaxf(sv0.w + tv0.w, 0.f);
        pk.h[4] = (__bf16)fmaxf(sv1.x + tv1.x, 0.f);
        pk.h[5] = (__bf16)fmaxf(sv1.y + tv1.y, 0.f);
        pk.h[6] = (__bf16)fmaxf(sv1.z + tv1.z, 0.f);
        pk.h[7] = (__bf16)fmaxf(sv1.w + tv1.w, 0.f);
        af[mi] = pk.v;
      }
      bf16x8 bg[4];
      #pragma unroll
      for (int ni = 0; ni < 4; ++ni)
        bg[ni] = *(const bf16x8*)(Bs + baddr[ni][s] + kt * 128);
      __builtin_amdgcn_s_setprio(1);
      #pragma unroll
      for (int mi = 0; mi < 4; ++mi)
        #pragma unroll
        for (int ni = 0; ni < 4; ++ni)
          acc[mi][ni] = __builtin_amdgcn_mfma_f32_16x16x32_bf16(
              af[mi], bg[ni], acc[mi][ni], 0, 0, 0);
      __builtin_amdgcn_s_setprio(0);
    }
  }

  // ---- epilogue: C/D layout col=lane&15, row=(lane>>4)*4+reg ----
  const int r4 = kl * 4;
  #pragma unroll
  for (int mi = 0; mi < 4; ++mi) {
    const size_t mrow = (size_t)bt * 64 + mi * 16 + r4;   // m = bt*U + u
    float* op0 = out + mrow * V_ + bn * 64 + cl;
    #pragma unroll
    for (int ni = 0; ni < 4; ++ni) {
      float* op = op0 + ni * 16;
      const f32x4 v = acc[mi][ni];
      op[0 * V_] = v[0];
      op[1 * V_] = v[1];
      op[2 * V_] = v[2];
      op[3 * V_] = v[3];
    }
  }
}

// ---------------------------------------------------------------------------
// Fallback (ws too small): round-1 fused kernel, f32 W in-loop.
// ---------------------------------------------------------------------------
__global__ __launch_bounds__(256, 2) void joiner_gemm_f32(
    const float* __restrict__ src, const float* __restrict__ tgt,
    const float* __restrict__ Wf, const float* __restrict__ bias,
    float* __restrict__ out)
{
  __shared__ char As[128 * 128];
  __shared__ char Bs[128 * 128];

  const int tid  = threadIdx.x;
  const int lane = tid & 63;
  const int wid  = tid >> 6;
  const int bn   = blockIdx.x & 7;
  const int bm   = blockIdx.x >> 3;
  const int bt0  = bm * 2;
  const int bb   = bt0 >> 7;
  const int sr0  = tid >> 3;
  const int sc8  = tid & 7;
  const int wm   = (wid >> 1) * 64;
  const int wn   = (wid & 1) * 64;

  f32x4 acc[4][4] = {};

  const float* srcp0 = src + (size_t)bt0 * D_ + sc8 * 8;
  const float* srcp1 = srcp0 + D_;
  const float* tgtp0 = tgt + ((size_t)bb * U_ + sr0) * D_ + sc8 * 8;
  const float* tgtp1 = tgtp0 + (size_t)32 * D_;

  for (int kt = 0; kt < 8; ++kt) {
    const int k0 = kt * 64;
    #pragma unroll
    for (int jj = 0; jj < 4; ++jj) {
      const int vr = sr0 + 32 * jj;
      const float* wp = Wf + (size_t)(bn * 128 + vr) * D_ + k0 + sc8 * 8;
      float4 w0 = *(const float4*)wp;
      float4 w1 = *(const float4*)(wp + 4);
      union { __bf16 h[8]; i32x4 x; } pk;
      pk.h[0] = (__bf16)w0.x; pk.h[1] = (__bf16)w0.y;
      pk.h[2] = (__bf16)w0.z; pk.h[3] = (__bf16)w0.w;
      pk.h[4] = (__bf16)w1.x; pk.h[5] = (__bf16)w1.y;
      pk.h[6] = (__bf16)w1.z; pk.h[7] = (__bf16)w1.w;
      *(i32x4*)(Bs + vr * 128 + ((sc8 ^ (vr & 7)) << 4)) = pk.x;
    }
    float4 s0a = *(const float4*)(srcp0 + k0), s0b = *(const float4*)(srcp0 + k0 + 4);
    float4 s1a = *(const float4*)(srcp1 + k0), s1b = *(const float4*)(srcp1 + k0 + 4);
    float4 t0a = *(const float4*)(tgtp0 + k0), t0b = *(const float4*)(tgtp0 + k0 + 4);
    float4 t1a = *(const float4*)(tgtp1 + k0), t1b = *(const float4*)(tgtp1 + k0 + 4);
    #pragma unroll
    for (int i = 0; i < 2; ++i) {
      const float4 sa = i ? s1a : s0a;
      const float4 sb = i ? s1b : s0b;
      #pragma unroll
      for (int jj = 0; jj < 2; ++jj) {
        const float4 ta = jj ? t1a : t0a;
        const float4 tb = jj ? t1b : t0b;
        const int r = i * 64 + jj * 32 + sr0;
        union { __bf16 h[8]; i32x4 x; } pk;
        pk.h[0] = (__bf16)fmaxf(sa.x + ta.x, 0.f);
        pk.h[1] = (__bf16)fmaxf(sa.y + ta.y, 0.f);
        pk.h[2] = (__bf16)fmaxf(sa.z + ta.z, 0.f);
        pk.h[3] = (__bf16)fmaxf(sa.w + ta.w, 0.f);
        pk.h[4] = (__bf16)fmaxf(sb.x + tb.x, 0.f);
        pk.h[5] = (__bf16)fmaxf(sb.y + tb.y, 0.f);
        pk.h[6] = (__bf16)fmaxf(sb.z + tb.z, 0.f);
        pk.h[7] = (__bf16)fmaxf(sb.w + tb.w, 0.f);
        *(i32x4*)(As + r * 128 + ((sc8 ^ (r & 7)) << 4)) = pk.x;
      }
    }
    __syncthreads();
    #pragma unroll
    for (int s = 0; s < 2; ++s) {
      const int kc = s * 4 + (lane >> 4);
      bf16x8 af[4], bg[4];
      #pragma unroll
      for (int mi = 0; mi < 4; ++mi) {
        const int r = wm + mi * 16 + (lane & 15);
        af[mi] = *(const bf16x8*)(As + r * 128 + ((kc ^ (r & 7)) << 4));
      }
      #pragma unroll
      for (int ni = 0; ni < 4; ++ni) {
        const int n = wn + ni * 16 + (lane & 15);
        bg[ni] = *(const bf16x8*)(Bs + n * 128 + ((kc ^ (n & 7)) << 4));
      }
      #pragma unroll
      for (int mi = 0; mi < 4; ++mi)
        #pragma unroll
        for (int ni = 0; ni < 4; ++ni)
          acc[mi][ni] = __builtin_amdgcn_mfma_f32_16x16x32_bf16(
              af[mi], bg[ni], acc[mi][ni], 0, 0, 0);
    }
    __syncthreads();
  }

  const int col = lane & 15;
  const int r4  = (lane >> 4) * 4;
  float bv[4];
  #pragma unroll
  for (int ni = 0; ni < 4; ++ni) bv[ni] = bias[bn * 128 + wn + ni * 16 + col];
  #pragma unroll
  for (int mi = 0; mi < 4; ++mi) {
    const size_t mrow = (size_t)bm * 128 + wm + mi * 16 + r4;
    float* op0 = out + mrow * V_ + bn * 128 + wn + col;
    #pragma unroll
    for (int ni = 0; ni < 4; ++ni) {
      float* op = op0 + ni * 16;
      const f32x4 v = acc[mi][ni];
      op[0 * V_] = v[0] + bv[ni];
      op[1 * V_] = v[1] + bv[ni];
      op[2 * V_] = v[2] + bv[ni];
      op[3 * V_] = v[3] + bv[ni];
    }
  }
}

extern "C" void kernel_launch(void* const* d_in, const int* in_sizes, int n_in,
                              void* d_out, int out_size, void* d_ws, size_t ws_size,
                              hipStream_t stream) {
  const float* src  = (const float*)d_in[0];
  const int*   sl   = (const int*)d_in[1];
  const float* tgt  = (const float*)d_in[2];
  const int*   tl   = (const int*)d_in[3];
  const float* W    = (const float*)d_in[4];
  const float* bias = (const float*)d_in[5];
  float* out  = (float*)d_out;
  float* tail = out + (size_t)M_ * V_;

  if (ws_size >= (size_t)V_ * D_ * sizeof(u16)) {
    u16* Wb = (u16*)d_ws;
    prep_w<<<256, 256, 0, stream>>>(W, sl, tl, Wb, tail);
    // 128 bt-groups x 16 v-slices = 2048 blocks of 512 threads
    joiner_gemm_direct<<<(T_ * B_ / 8) * (V_ / 64), 512, 0, stream>>>(
        src, tgt, Wb, bias, out);
  } else {
    tail_k<<<1, 64, 0, stream>>>(sl, tl, tail);
    joiner_gemm_f32<<<(M_ / 128) * (V_ / 128), 256, 0, stream>>>(
        src, tgt, W, bias, out);
  }
}

// Round 7
// 105.120 us; speedup vs baseline: 2.5167x; 2.5167x over previous
//
#include <hip/hip_runtime.h>

typedef unsigned short u16;
typedef float  f32x4  __attribute__((ext_vector_type(4)));
typedef int    i32x4  __attribute__((ext_vector_type(4)));
typedef __bf16 bf16x8 __attribute__((ext_vector_type(8)));

#define AS1 __attribute__((address_space(1)))
#define AS3 __attribute__((address_space(3)))

__device__ __forceinline__ void gload_lds16(const void* g, void* l) {
  __builtin_amdgcn_global_load_lds((AS1 void*)g, (AS3 void*)l, 16, 0, 0);
}

// Problem constants
constexpr int B_ = 8, T_ = 128, U_ = 64, D_ = 512, V_ = 1024;
constexpr int M_ = B_ * T_ * U_;   // 65536

// ---------------------------------------------------------------------------
// prep_w: W (V,D) f32 -> bf16 ws with XOR-swizzle pre-applied per 64-col
// K-tile (16B chunk c of row v stored at slot c^(v&7)); block 0 also writes
// the lengths pass-through (as f32 values).
// ---------------------------------------------------------------------------
__global__ void prep_w(const float* __restrict__ W,
                       const int* __restrict__ sl, const int* __restrict__ tl,
                       u16* __restrict__ Wb, float* __restrict__ tail) {
  if (blockIdx.x == 0 && threadIdx.x < 16) {
    const int t = threadIdx.x;
    tail[t] = (t < 8) ? (float)sl[t] : (float)tl[t - 8];
  }
  const int tid = blockIdx.x * 256 + threadIdx.x;   // 65536 threads
  const int v  = tid >> 6;
  const int cs = tid & 63;
  const float* sp = W + (size_t)v * D_ + cs * 8;
  float4 w0 = *(const float4*)sp;
  float4 w1 = *(const float4*)(sp + 4);
  union { __bf16 h[8]; i32x4 x; } pk;
  pk.h[0] = (__bf16)w0.x; pk.h[1] = (__bf16)w0.y;
  pk.h[2] = (__bf16)w0.z; pk.h[3] = (__bf16)w0.w;
  pk.h[4] = (__bf16)w1.x; pk.h[5] = (__bf16)w1.y;
  pk.h[6] = (__bf16)w1.z; pk.h[7] = (__bf16)w1.w;
  const int dc = (cs >> 3) * 8 + ((cs & 7) ^ (v & 7));
  *(i32x4*)(Wb + (size_t)v * D_ + dc * 8) = pk.x;
}

__global__ void tail_k(const int* __restrict__ sl, const int* __restrict__ tl,
                       float* __restrict__ tail) {
  const int t = threadIdx.x;
  if (t < 8)       tail[t] = (float)sl[t];
  else if (t < 16) tail[t] = (float)tl[t - 8];
}

// ---------------------------------------------------------------------------
// Fused joiner GEMM — R1 geometry (BM=BN=128, BK=64, 256 thr, 4 waves 2x2,
// wave tile 64x64) with a counted-drain pipeline (T4, plain HIP):
//  - B double-buffered (2x16KB), A single (16KB) -> 48KB LDS, 3 blocks/CU.
//  - Next tile's A f32 loads -> regs and B global_load_lds -> other buffer
//    are issued BEFORE compute, so they age a full MFMA phase (~600cyc).
//  - Raw s_barrier (no implicit vmcnt(0) drain). Post-compute barrier drains
//    nothing; pre-compute barrier's explicit vmcnt(0)/lgkmcnt(0) drains only
//    aged ops. sched_barrier(0) pins phase edges (no cross-phase hoist/sink).
// ---------------------------------------------------------------------------
__global__ __launch_bounds__(256, 3) void joiner_gemm(
    const float* __restrict__ src, const float* __restrict__ tgt,
    const u16* __restrict__ Wb, const float* __restrict__ bias,
    float* __restrict__ out)
{
  __shared__ __align__(16) char As[16384];       // 128 rows x 64 bf16
  __shared__ __align__(16) char Bs[2][16384];    // dbuf

  const int tid  = threadIdx.x;
  const int lane = tid & 63;
  const int wid  = tid >> 6;
  const int bn   = blockIdx.x & 7;   // 8 N-tiles
  const int bm   = blockIdx.x >> 3;  // 512 M-tiles
  const int bt0  = bm * 2;           // two (b,t) rows per M-tile (U=64)
  const int bb   = bt0 >> 7;         // batch
  const int sr0  = tid >> 3;         // staging row 0..31
  const int sc8  = tid & 7;          // staging 16B chunk 0..7
  const int wm   = (wid >> 1) * 64;
  const int wn   = (wid & 1) * 64;

  f32x4 acc[4][4] = {};

  const float* srcp0 = src + (size_t)bt0 * D_ + sc8 * 8;
  const float* srcp1 = srcp0 + D_;
  const float* tgtp0 = tgt + ((size_t)bb * U_ + sr0) * D_ + sc8 * 8;
  const float* tgtp1 = tgtp0 + (size_t)32 * D_;

  float bv[4];
  #pragma unroll
  for (int ni = 0; ni < 4; ++ni)
    bv[ni] = bias[bn * 128 + wn + ni * 16 + (lane & 15)];

  // B staging bases (16 x 1KB stripes, 4 per wave)
  const u16* bbase[4];
  #pragma unroll
  for (int q = 0; q < 4; ++q) {
    const int i   = wid * 4 + q;
    const int row = i * 8 + (lane >> 3);
    bbase[q] = Wb + (size_t)(bn * 128 + row) * D_ + (lane & 7) * 8;
  }

  float4 pS0a, pS0b, pS1a, pS1b, pT0a, pT0b, pT1a, pT1b;   // A prefetch regs

  auto loadA = [&](int kt) {     // f32 loads FIRST (older in vmcnt queue)
    const int k0 = kt * 64;
    pS0a = *(const float4*)(srcp0 + k0); pS0b = *(const float4*)(srcp0 + k0 + 4);
    pS1a = *(const float4*)(srcp1 + k0); pS1b = *(const float4*)(srcp1 + k0 + 4);
    pT0a = *(const float4*)(tgtp0 + k0); pT0b = *(const float4*)(tgtp0 + k0 + 4);
    pT1a = *(const float4*)(tgtp1 + k0); pT1b = *(const float4*)(tgtp1 + k0 + 4);
  };
  auto issueB = [&](int kt, int nb) {   // DMA after (newer -> vmcnt(4) at use)
    #pragma unroll
    for (int q = 0; q < 4; ++q)
      gload_lds16(bbase[q] + kt * 64, Bs[nb] + (wid * 4 + q) * 1024);
  };

  auto expandA = [&]() {   // relu(src+tgt) -> bf16, swizzled ds_write (x4 rows)
    #pragma unroll
    for (int i = 0; i < 2; ++i) {
      const float4 sa = i ? pS1a : pS0a;
      const float4 sb = i ? pS1b : pS0b;
      #pragma unroll
      for (int j = 0; j < 2; ++j) {
        const float4 ta = j ? pT1a : pT0a;
        const float4 tb = j ? pT1b : pT0b;
        const int r = i * 64 + j * 32 + sr0;
        union { __bf16 h[8]; i32x4 x; } pk;
        pk.h[0] = (__bf16)fmaxf(sa.x + ta.x, 0.f);
        pk.h[1] = (__bf16)fmaxf(sa.y + ta.y, 0.f);
        pk.h[2] = (__bf16)fmaxf(sa.z + ta.z, 0.f);
        pk.h[3] = (__bf16)fmaxf(sa.w + ta.w, 0.f);
        pk.h[4] = (__bf16)fmaxf(sb.x + tb.x, 0.f);
        pk.h[5] = (__bf16)fmaxf(sb.y + tb.y, 0.f);
        pk.h[6] = (__bf16)fmaxf(sb.z + tb.z, 0.f);
        pk.h[7] = (__bf16)fmaxf(sb.w + tb.w, 0.f);
        *(i32x4*)(As + r * 128 + ((sc8 ^ (r & 7)) << 4)) = pk.x;
      }
    }
  };

  auto compute = [&](int cb) {
    #pragma unroll
    for (int s = 0; s < 2; ++s) {
      const int kc = s * 4 + (lane >> 4);
      bf16x8 af[4], bg[4];
      #pragma unroll
      for (int mi = 0; mi < 4; ++mi) {
        const int r = wm + mi * 16 + (lane & 15);
        af[mi] = *(const bf16x8*)(As + r * 128 + ((kc ^ (r & 7)) << 4));
      }
      #pragma unroll
      for (int ni = 0; ni < 4; ++ni) {
        const int n = wn + ni * 16 + (lane & 15);
        bg[ni] = *(const bf16x8*)(Bs[cb] + n * 128 + ((kc ^ (n & 7)) << 4));
      }
      __builtin_amdgcn_s_setprio(1);
      #pragma unroll
      for (int mi = 0; mi < 4; ++mi)
        #pragma unroll
        for (int ni = 0; ni < 4; ++ni)
          acc[mi][ni] = __builtin_amdgcn_mfma_f32_16x16x32_bf16(
              af[mi], bg[ni], acc[mi][ni], 0, 0, 0);
      __builtin_amdgcn_s_setprio(0);
    }
  };

  // ---- prologue: tile 0 ----
  loadA(0);
  issueB(0, 0);
  expandA();                                     // compiler waits vmcnt(4)
  asm volatile("s_waitcnt vmcnt(0) lgkmcnt(0)" ::: "memory");
  __builtin_amdgcn_sched_barrier(0);
  __builtin_amdgcn_s_barrier();
  __builtin_amdgcn_sched_barrier(0);

  // ---- K-loop: per tile, prefetch -> compute -> barrier -> expand -> barrier
  for (int kt = 0; kt < 8; ++kt) {
    if (kt < 7) {
      loadA(kt + 1);                             // in flight under MFMA
      issueB(kt + 1, (kt + 1) & 1);              // DMA -> other buffer
    }
    __builtin_amdgcn_sched_barrier(0);           // issue before compute
    compute(kt & 1);
    if (kt < 7) {
      __builtin_amdgcn_sched_barrier(0);         // no ds_read sink past barrier
      __builtin_amdgcn_s_barrier();              // A readers done (NO drain)
      expandA();                                 // vmcnt(4): f32 aged ~600cyc
      asm volatile("s_waitcnt vmcnt(0) lgkmcnt(0)" ::: "memory");  // aged DMA + ds_write flush
      __builtin_amdgcn_sched_barrier(0);
      __builtin_amdgcn_s_barrier();              // A+B(kt+1) visible
      __builtin_amdgcn_sched_barrier(0);
    }
  }

  // ---- epilogue: C/D layout col=lane&15, row=(lane>>4)*4+reg ----
  const int col = lane & 15;
  const int r4  = (lane >> 4) * 4;
  #pragma unroll
  for (int mi = 0; mi < 4; ++mi) {
    const size_t mrow = (size_t)bm * 128 + wm + mi * 16 + r4;
    float* op0 = out + mrow * V_ + bn * 128 + wn + col;
    #pragma unroll
    for (int ni = 0; ni < 4; ++ni) {
      float* op = op0 + ni * 16;
      const f32x4 v = acc[mi][ni];
      op[0 * V_] = v[0] + bv[ni];
      op[1 * V_] = v[1] + bv[ni];
      op[2 * V_] = v[2] + bv[ni];
      op[3 * V_] = v[3] + bv[ni];
    }
  }
}

// ---------------------------------------------------------------------------
// Fallback (ws too small): round-1 fused kernel, f32 W in-loop.
// ---------------------------------------------------------------------------
__global__ __launch_bounds__(256, 2) void joiner_gemm_f32(
    const float* __restrict__ src, const float* __restrict__ tgt,
    const float* __restrict__ Wf, const float* __restrict__ bias,
    float* __restrict__ out)
{
  __shared__ char As[128 * 128];
  __shared__ char Bs[128 * 128];

  const int tid  = threadIdx.x;
  const int lane = tid & 63;
  const int wid  = tid >> 6;
  const int bn   = blockIdx.x & 7;
  const int bm   = blockIdx.x >> 3;
  const int bt0  = bm * 2;
  const int bb   = bt0 >> 7;
  const int sr0  = tid >> 3;
  const int sc8  = tid & 7;
  const int wm   = (wid >> 1) * 64;
  const int wn   = (wid & 1) * 64;

  f32x4 acc[4][4] = {};

  const float* srcp0 = src + (size_t)bt0 * D_ + sc8 * 8;
  const float* srcp1 = srcp0 + D_;
  const float* tgtp0 = tgt + ((size_t)bb * U_ + sr0) * D_ + sc8 * 8;
  const float* tgtp1 = tgtp0 + (size_t)32 * D_;

  for (int kt = 0; kt < 8; ++kt) {
    const int k0 = kt * 64;
    #pragma unroll
    for (int jj = 0; jj < 4; ++jj) {
      const int vr = sr0 + 32 * jj;
      const float* wp = Wf + (size_t)(bn * 128 + vr) * D_ + k0 + sc8 * 8;
      float4 w0 = *(const float4*)wp;
      float4 w1 = *(const float4*)(wp + 4);
      union { __bf16 h[8]; i32x4 x; } pk;
      pk.h[0] = (__bf16)w0.x; pk.h[1] = (__bf16)w0.y;
      pk.h[2] = (__bf16)w0.z; pk.h[3] = (__bf16)w0.w;
      pk.h[4] = (__bf16)w1.x; pk.h[5] = (__bf16)w1.y;
      pk.h[6] = (__bf16)w1.z; pk.h[7] = (__bf16)w1.w;
      *(i32x4*)(Bs + vr * 128 + ((sc8 ^ (vr & 7)) << 4)) = pk.x;
    }
    float4 s0a = *(const float4*)(srcp0 + k0), s0b = *(const float4*)(srcp0 + k0 + 4);
    float4 s1a = *(const float4*)(srcp1 + k0), s1b = *(const float4*)(srcp1 + k0 + 4);
    float4 t0a = *(const float4*)(tgtp0 + k0), t0b = *(const float4*)(tgtp0 + k0 + 4);
    float4 t1a = *(const float4*)(tgtp1 + k0), t1b = *(const float4*)(tgtp1 + k0 + 4);
    #pragma unroll
    for (int i = 0; i < 2; ++i) {
      const float4 sa = i ? s1a : s0a;
      const float4 sb = i ? s1b : s0b;
      #pragma unroll
      for (int jj = 0; jj < 2; ++jj) {
        const float4 ta = jj ? t1a : t0a;
        const float4 tb = jj ? t1b : t0b;
        const int r = i * 64 + jj * 32 + sr0;
        union { __bf16 h[8]; i32x4 x; } pk;
        pk.h[0] = (__bf16)fmaxf(sa.x + ta.x, 0.f);
        pk.h[1] = (__bf16)fmaxf(sa.y + ta.y, 0.f);
        pk.h[2] = (__bf16)fmaxf(sa.z + ta.z, 0.f);
        pk.h[3] = (__bf16)fmaxf(sa.w + ta.w, 0.f);
        pk.h[4] = (__bf16)fmaxf(sb.x + tb.x, 0.f);
        pk.h[5] = (__bf16)fmaxf(sb.y + tb.y, 0.f);
        pk.h[6] = (__bf16)fmaxf(sb.z + tb.z, 0.f);
        pk.h[7] = (__bf16)fmaxf(sb.w + tb.w, 0.f);
        *(i32x4*)(As + r * 128 + ((sc8 ^ (r & 7)) << 4)) = pk.x;
      }
    }
    __syncthreads();
    #pragma unroll
    for (int s = 0; s < 2; ++s) {
      const int kc = s * 4 + (lane >> 4);
      bf16x8 af[4], bg[4];
      #pragma unroll
      for (int mi = 0; mi < 4; ++mi) {
        const int r = wm + mi * 16 + (lane & 15);
        af[mi] = *(const bf16x8*)(As + r * 128 + ((kc ^ (r & 7)) << 4));
      }
      #pragma unroll
      for (int ni = 0; ni < 4; ++ni) {
        const int n = wn + ni * 16 + (lane & 15);
        bg[ni] = *(const bf16x8*)(Bs + n * 128 + ((kc ^ (n & 7)) << 4));
      }
      #pragma unroll
      for (int mi = 0; mi < 4; ++mi)
        #pragma unroll
        for (int ni = 0; ni < 4; ++ni)
          acc[mi][ni] = __builtin_amdgcn_mfma_f32_16x16x32_bf16(
              af[mi], bg[ni], acc[mi][ni], 0, 0, 0);
    }
    __syncthreads();
  }

  const int col = lane & 15;
  const int r4  = (lane >> 4) * 4;
  float bv[4];
  #pragma unroll
  for (int ni = 0; ni < 4; ++ni) bv[ni] = bias[bn * 128 + wn + ni * 16 + col];
  #pragma unroll
  for (int mi = 0; mi < 4; ++mi) {
    const size_t mrow = (size_t)bm * 128 + wm + mi * 16 + r4;
    float* op0 = out + mrow * V_ + bn * 128 + wn + col;
    #pragma unroll
    for (int ni = 0; ni < 4; ++ni) {
      float* op = op0 + ni * 16;
      const f32x4 v = acc[mi][ni];
      op[0 * V_] = v[0] + bv[ni];
      op[1 * V_] = v[1] + bv[ni];
      op[2 * V_] = v[2] + bv[ni];
      op[3 * V_] = v[3] + bv[ni];
    }
  }
}

extern "C" void kernel_launch(void* const* d_in, const int* in_sizes, int n_in,
                              void* d_out, int out_size, void* d_ws, size_t ws_size,
                              hipStream_t stream) {
  const float* src  = (const float*)d_in[0];
  const int*   sl   = (const int*)d_in[1];
  const float* tgt  = (const float*)d_in[2];
  const int*   tl   = (const int*)d_in[3];
  const float* W    = (const float*)d_in[4];
  const float* bias = (const float*)d_in[5];
  float* out  = (float*)d_out;
  float* tail = out + (size_t)M_ * V_;

  if (ws_size >= (size_t)V_ * D_ * sizeof(u16)) {
    u16* Wb = (u16*)d_ws;
    prep_w<<<256, 256, 0, stream>>>(W, sl, tl, Wb, tail);
    joiner_gemm<<<(M_ / 128) * (V_ / 128), 256, 0, stream>>>(
        src, tgt, Wb, bias, out);
  } else {
    tail_k<<<1, 64, 0, stream>>>(sl, tl, tail);
    joiner_gemm_f32<<<(M_ / 128) * (V_ / 128), 256, 0, stream>>>(
        src, tgt, W, bias, out);
  }
}

// Round 8
// 103.369 us; speedup vs baseline: 2.5593x; 1.0169x over previous
//
#include <hip/hip_runtime.h>

typedef unsigned short u16;
typedef float  f32x4  __attribute__((ext_vector_type(4)));
typedef int    i32x4  __attribute__((ext_vector_type(4)));
typedef __bf16 bf16x8 __attribute__((ext_vector_type(8)));

#define AS1 __attribute__((address_space(1)))
#define AS3 __attribute__((address_space(3)))

// Problem constants
constexpr int B_ = 8, T_ = 128, U_ = 64, D_ = 512, V_ = 1024;
constexpr int M_ = B_ * T_ * U_;   // 65536

// ---------------------------------------------------------------------------
// prep_w: W (V,D) f32 -> bf16 in MFMA-fragment order:
//   Wb2[((vg*16 + kc)*64 + ko*16 + vc)*8 + ke]
// where v = vg*16+vc, k = kc*32 + ko*8 + ke. A 16x16x32 B-fragment for
// (v-group vg, k-chunk kc) is then 64 consecutive lanes x 16B -> one
// coalesced global_load_dwordx4 per fragment, no LDS needed for B.
// Block 0 also writes the lengths pass-through (as f32 values).
// ---------------------------------------------------------------------------
__global__ void prep_w(const float* __restrict__ W,
                       const int* __restrict__ sl, const int* __restrict__ tl,
                       u16* __restrict__ Wb2, float* __restrict__ tail) {
  if (blockIdx.x == 0 && threadIdx.x < 16) {
    const int t = threadIdx.x;
    tail[t] = (t < 8) ? (float)sl[t] : (float)tl[t - 8];
  }
  const int tid = blockIdx.x * 256 + threadIdx.x;   // 65536 threads
  const int v  = tid >> 6;        // 0..1023
  const int cs = tid & 63;        // 8-elem chunk, k = cs*8
  const float* sp = W + (size_t)v * D_ + cs * 8;
  float4 w0 = *(const float4*)sp;
  float4 w1 = *(const float4*)(sp + 4);
  union { __bf16 h[8]; i32x4 x; } pk;
  pk.h[0] = (__bf16)w0.x; pk.h[1] = (__bf16)w0.y;
  pk.h[2] = (__bf16)w0.z; pk.h[3] = (__bf16)w0.w;
  pk.h[4] = (__bf16)w1.x; pk.h[5] = (__bf16)w1.y;
  pk.h[6] = (__bf16)w1.z; pk.h[7] = (__bf16)w1.w;
  const int vg = v >> 4, vc = v & 15;
  const int kc = cs >> 2, ko = cs & 3;
  *(i32x4*)(Wb2 + (((size_t)(vg * 16 + kc) * 64 + ko * 16 + vc) * 8)) = pk.x;
}

__global__ void tail_k(const int* __restrict__ sl, const int* __restrict__ tl,
                       float* __restrict__ tail) {
  const int t = threadIdx.x;
  if (t < 8)       tail[t] = (float)sl[t];
  else if (t < 16) tail[t] = (float)tl[t - 8];
}

// ---------------------------------------------------------------------------
// Fused joiner GEMM — B-in-registers variant.
// BM=BN=128, BK=64, 256 thr (4 waves 2x2), wave tile 64x64,
// 4x4 x mfma_f32_16x16x32_bf16.
//  - B fragments: coalesced global_load_dwordx4 from fragment-ordered Wb2
//    (L2-resident, 1MB) straight into 32 VGPRs. NO LDS, NO DMA for B.
//  - A: R1's proven path (f32 loads -> relu/cvt -> swizzled ds_write),
//    single 16KB buffer. LDS traffic ~halved vs R1.
//  - 2 raw s_barriers per tile, NO vmcnt drains anywhere: register loads
//    need no cross-wave fence; only lgkmcnt(0) for ds_writes.
//  - f32 A-loads issued before compute (age ~600cyc under MFMA);
//    bg loads issued right after barrier (age across expand).
// ---------------------------------------------------------------------------
__global__ __launch_bounds__(256, 3) void joiner_gemm(
    const float* __restrict__ src, const float* __restrict__ tgt,
    const u16* __restrict__ Wb2, const float* __restrict__ bias,
    float* __restrict__ out)
{
  __shared__ __align__(16) char As[16384];   // 128 rows x 64 bf16, swizzled

  const int tid  = threadIdx.x;
  const int lane = tid & 63;
  const int wid  = tid >> 6;
  const int bn   = blockIdx.x & 7;   // 8 N-tiles
  const int bm   = blockIdx.x >> 3;  // 512 M-tiles
  const int bt0  = bm * 2;           // two (b,t) rows per M-tile (U=64)
  const int bb   = bt0 >> 7;         // batch
  const int sr0  = tid >> 3;         // staging row 0..31
  const int sc8  = tid & 7;          // staging 16B chunk 0..7
  const int wm   = (wid >> 1) * 64;
  const int wn   = (wid & 1) * 64;

  f32x4 acc[4][4] = {};

  const float* srcp0 = src + (size_t)bt0 * D_ + sc8 * 8;
  const float* srcp1 = srcp0 + D_;
  const float* tgtp0 = tgt + ((size_t)bb * U_ + sr0) * D_ + sc8 * 8;
  const float* tgtp1 = tgtp0 + (size_t)32 * D_;

  float bv[4];
  #pragma unroll
  for (int ni = 0; ni < 4; ++ni)
    bv[ni] = bias[bn * 128 + wn + ni * 16 + (lane & 15)];

  // B fragment bases: vg = bn*8 + wn/16 + ni; frag (kc) at +kc*1024 elems
  const u16* bfr[4];
  #pragma unroll
  for (int ni = 0; ni < 4; ++ni) {
    const int vg = bn * 8 + (wn >> 4) + ni;
    bfr[ni] = Wb2 + ((size_t)vg * 16 * 64 + lane) * 8;
  }

  float4 pS0a, pS0b, pS1a, pS1b, pT0a, pT0b, pT1a, pT1b;  // A prefetch regs
  bf16x8 bg[4][2];                                        // B frags, K-tile

  auto loadA = [&](int kt) {
    const int k0 = kt * 64;
    pS0a = *(const float4*)(srcp0 + k0); pS0b = *(const float4*)(srcp0 + k0 + 4);
    pS1a = *(const float4*)(srcp1 + k0); pS1b = *(const float4*)(srcp1 + k0 + 4);
    pT0a = *(const float4*)(tgtp0 + k0); pT0b = *(const float4*)(tgtp0 + k0 + 4);
    pT1a = *(const float4*)(tgtp1 + k0); pT1b = *(const float4*)(tgtp1 + k0 + 4);
  };

  auto loadBg = [&](int kt) {   // 8 coalesced dwordx4, global->reg
    #pragma unroll
    for (int ni = 0; ni < 4; ++ni)
      #pragma unroll
      for (int s = 0; s < 2; ++s)
        bg[ni][s] = *(const bf16x8*)(bfr[ni] + (size_t)(kt * 2 + s) * 512);
  };

  auto expandA = [&]() {   // relu(src+tgt) -> bf16, swizzled ds_write (x4 rows)
    #pragma unroll
    for (int i = 0; i < 2; ++i) {
      const float4 sa = i ? pS1a : pS0a;
      const float4 sb = i ? pS1b : pS0b;
      #pragma unroll
      for (int j = 0; j < 2; ++j) {
        const float4 ta = j ? pT1a : pT0a;
        const float4 tb = j ? pT1b : pT0b;
        const int r = i * 64 + j * 32 + sr0;
        union { __bf16 h[8]; i32x4 x; } pk;
        pk.h[0] = (__bf16)fmaxf(sa.x + ta.x, 0.f);
        pk.h[1] = (__bf16)fmaxf(sa.y + ta.y, 0.f);
        pk.h[2] = (__bf16)fmaxf(sa.z + ta.z, 0.f);
        pk.h[3] = (__bf16)fmaxf(sa.w + ta.w, 0.f);
        pk.h[4] = (__bf16)fmaxf(sb.x + tb.x, 0.f);
        pk.h[5] = (__bf16)fmaxf(sb.y + tb.y, 0.f);
        pk.h[6] = (__bf16)fmaxf(sb.z + tb.z, 0.f);
        pk.h[7] = (__bf16)fmaxf(sb.w + tb.w, 0.f);
        *(i32x4*)(As + r * 128 + ((sc8 ^ (r & 7)) << 4)) = pk.x;
      }
    }
  };

  auto compute = [&]() {
    #pragma unroll
    for (int s = 0; s < 2; ++s) {
      const int kc = s * 4 + (lane >> 4);
      bf16x8 af[4];
      #pragma unroll
      for (int mi = 0; mi < 4; ++mi) {
        const int r = wm + mi * 16 + (lane & 15);
        af[mi] = *(const bf16x8*)(As + r * 128 + ((kc ^ (r & 7)) << 4));
      }
      __builtin_amdgcn_s_setprio(1);
      #pragma unroll
      for (int mi = 0; mi < 4; ++mi)
        #pragma unroll
        for (int ni = 0; ni < 4; ++ni)
          acc[mi][ni] = __builtin_amdgcn_mfma_f32_16x16x32_bf16(
              af[mi], bg[ni][s], acc[mi][ni], 0, 0, 0);
      __builtin_amdgcn_s_setprio(0);
    }
  };

  // ---- prologue: tile 0 ----
  loadA(0);
  expandA();                       // waits its f32 loads
  loadBg(0);                       // in flight; compute waits as needed
  asm volatile("s_waitcnt lgkmcnt(0)" ::: "memory");
  __builtin_amdgcn_sched_barrier(0);
  __builtin_amdgcn_s_barrier();
  __builtin_amdgcn_sched_barrier(0);

  // ---- K-loop ----
  for (int kt = 0; kt < 8; ++kt) {
    if (kt < 7) loadA(kt + 1);                   // ages under compute
    __builtin_amdgcn_sched_barrier(0);
    compute();                                   // af(LDS) x bg(regs)
    __builtin_amdgcn_sched_barrier(0);
    __builtin_amdgcn_s_barrier();                // af reads done (no drain)
    __builtin_amdgcn_sched_barrier(0);
    if (kt < 7) {
      loadBg(kt + 1);                            // bg regs free; ages over expand
      expandA();                                 // waits f32 (aged), not bg
      asm volatile("s_waitcnt lgkmcnt(0)" ::: "memory");  // ds_writes visible
      __builtin_amdgcn_sched_barrier(0);
      __builtin_amdgcn_s_barrier();              // A(kt+1) ready
      __builtin_amdgcn_sched_barrier(0);
    }
  }

  // ---- epilogue: C/D layout col=lane&15, row=(lane>>4)*4+reg ----
  const int col = lane & 15;
  const int r4  = (lane >> 4) * 4;
  #pragma unroll
  for (int mi = 0; mi < 4; ++mi) {
    const size_t mrow = (size_t)bm * 128 + wm + mi * 16 + r4;
    float* op0 = out + mrow * V_ + bn * 128 + wn + col;
    #pragma unroll
    for (int ni = 0; ni < 4; ++ni) {
      float* op = op0 + ni * 16;
      const f32x4 v = acc[mi][ni];
      op[0 * V_] = v[0] + bv[ni];
      op[1 * V_] = v[1] + bv[ni];
      op[2 * V_] = v[2] + bv[ni];
      op[3 * V_] = v[3] + bv[ni];
    }
  }
}

// ---------------------------------------------------------------------------
// Fallback (ws too small): round-1 fused kernel, f32 W in-loop.
// ---------------------------------------------------------------------------
__global__ __launch_bounds__(256, 2) void joiner_gemm_f32(
    const float* __restrict__ src, const float* __restrict__ tgt,
    const float* __restrict__ Wf, const float* __restrict__ bias,
    float* __restrict__ out)
{
  __shared__ char As[128 * 128];
  __shared__ char Bs[128 * 128];

  const int tid  = threadIdx.x;
  const int lane = tid & 63;
  const int wid  = tid >> 6;
  const int bn   = blockIdx.x & 7;
  const int bm   = blockIdx.x >> 3;
  const int bt0  = bm * 2;
  const int bb   = bt0 >> 7;
  const int sr0  = tid >> 3;
  const int sc8  = tid & 7;
  const int wm   = (wid >> 1) * 64;
  const int wn   = (wid & 1) * 64;

  f32x4 acc[4][4] = {};

  const float* srcp0 = src + (size_t)bt0 * D_ + sc8 * 8;
  const float* srcp1 = srcp0 + D_;
  const float* tgtp0 = tgt + ((size_t)bb * U_ + sr0) * D_ + sc8 * 8;
  const float* tgtp1 = tgtp0 + (size_t)32 * D_;

  for (int kt = 0; kt < 8; ++kt) {
    const int k0 = kt * 64;
    #pragma unroll
    for (int jj = 0; jj < 4; ++jj) {
      const int vr = sr0 + 32 * jj;
      const float* wp = Wf + (size_t)(bn * 128 + vr) * D_ + k0 + sc8 * 8;
      float4 w0 = *(const float4*)wp;
      float4 w1 = *(const float4*)(wp + 4);
      union { __bf16 h[8]; i32x4 x; } pk;
      pk.h[0] = (__bf16)w0.x; pk.h[1] = (__bf16)w0.y;
      pk.h[2] = (__bf16)w0.z; pk.h[3] = (__bf16)w0.w;
      pk.h[4] = (__bf16)w1.x; pk.h[5] = (__bf16)w1.y;
      pk.h[6] = (__bf16)w1.z; pk.h[7] = (__bf16)w1.w;
      *(i32x4*)(Bs + vr * 128 + ((sc8 ^ (vr & 7)) << 4)) = pk.x;
    }
    float4 s0a = *(const float4*)(srcp0 + k0), s0b = *(const float4*)(srcp0 + k0 + 4);
    float4 s1a = *(const float4*)(srcp1 + k0), s1b = *(const float4*)(srcp1 + k0 + 4);
    float4 t0a = *(const float4*)(tgtp0 + k0), t0b = *(const float4*)(tgtp0 + k0 + 4);
    float4 t1a = *(const float4*)(tgtp1 + k0), t1b = *(const float4*)(tgtp1 + k0 + 4);
    #pragma unroll
    for (int i = 0; i < 2; ++i) {
      const float4 sa = i ? s1a : s0a;
      const float4 sb = i ? s1b : s0b;
      #pragma unroll
      for (int jj = 0; jj < 2; ++jj) {
        const float4 ta = jj ? t1a : t0a;
        const float4 tb = jj ? t1b : t0b;
        const int r = i * 64 + jj * 32 + sr0;
        union { __bf16 h[8]; i32x4 x; } pk;
        pk.h[0] = (__bf16)fmaxf(sa.x + ta.x, 0.f);
        pk.h[1] = (__bf16)fmaxf(sa.y + ta.y, 0.f);
        pk.h[2] = (__bf16)fmaxf(sa.z + ta.z, 0.f);
        pk.h[3] = (__bf16)fmaxf(sa.w + ta.w, 0.f);
        pk.h[4] = (__bf16)fmaxf(sb.x + tb.x, 0.f);
        pk.h[5] = (__bf16)fmaxf(sb.y + tb.y, 0.f);
        pk.h[6] = (__bf16)fmaxf(sb.z + tb.z, 0.f);
        pk.h[7] = (__bf16)fmaxf(sb.w + tb.w, 0.f);
        *(i32x4*)(As + r * 128 + ((sc8 ^ (r & 7)) << 4)) = pk.x;
      }
    }
    __syncthreads();
    #pragma unroll
    for (int s = 0; s < 2; ++s) {
      const int kc = s * 4 + (lane >> 4);
      bf16x8 af[4], bg[4];
      #pragma unroll
      for (int mi = 0; mi < 4; ++mi) {
        const int r = wm + mi * 16 + (lane & 15);
        af[mi] = *(const bf16x8*)(As + r * 128 + ((kc ^ (r & 7)) << 4));
      }
      #pragma unroll
      for (int ni = 0; ni < 4; ++ni) {
        const int n = wn + ni * 16 + (lane & 15);
        bg[ni] = *(const bf16x8*)(Bs + n * 128 + ((kc ^ (n & 7)) << 4));
      }
      #pragma unroll
      for (int mi = 0; mi < 4; ++mi)
        #pragma unroll
        for (int ni = 0; ni < 4; ++ni)
          acc[mi][ni] = __builtin_amdgcn_mfma_f32_16x16x32_bf16(
              af[mi], bg[ni], acc[mi][ni], 0, 0, 0);
    }
    __syncthreads();
  }

  const int col = lane & 15;
  const int r4  = (lane >> 4) * 4;
  float bv[4];
  #pragma unroll
  for (int ni = 0; ni < 4; ++ni) bv[ni] = bias[bn * 128 + wn + ni * 16 + col];
  #pragma unroll
  for (int mi = 0; mi < 4; ++mi) {
    const size_t mrow = (size_t)bm * 128 + wm + mi * 16 + r4;
    float* op0 = out + mrow * V_ + bn * 128 + wn + col;
    #pragma unroll
    for (int ni = 0; ni < 4; ++ni) {
      float* op = op0 + ni * 16;
      const f32x4 v = acc[mi][ni];
      op[0 * V_] = v[0] + bv[ni];
      op[1 * V_] = v[1] + bv[ni];
      op[2 * V_] = v[2] + bv[ni];
      op[3 * V_] = v[3] + bv[ni];
    }
  }
}

extern "C" void kernel_launch(void* const* d_in, const int* in_sizes, int n_in,
                              void* d_out, int out_size, void* d_ws, size_t ws_size,
                              hipStream_t stream) {
  const float* src  = (const float*)d_in[0];
  const int*   sl   = (const int*)d_in[1];
  const float* tgt  = (const float*)d_in[2];
  const int*   tl   = (const int*)d_in[3];
  const float* W    = (const float*)d_in[4];
  const float* bias = (const float*)d_in[5];
  float* out  = (float*)d_out;
  float* tail = out + (size_t)M_ * V_;

  if (ws_size >= (size_t)V_ * D_ * sizeof(u16)) {
    u16* Wb2 = (u16*)d_ws;
    prep_w<<<256, 256, 0, stream>>>(W, sl, tl, Wb2, tail);
    joiner_gemm<<<(M_ / 128) * (V_ / 128), 256, 0, stream>>>(
        src, tgt, Wb2, bias, out);
  } else {
    tail_k<<<1, 64, 0, stream>>>(sl, tl, tail);
    joiner_gemm_f32<<<(M_ / 128) * (V_ / 128), 256, 0, stream>>>(
        src, tgt, W, bias, out);
  }
}